// Round 5
// baseline (375.248 us; speedup 1.0000x reference)
//
#include <hip/hip_runtime.h>

#define B_ 1024
#define D_ 784
#define H_ 1024
#define BH_ (B_ * H_)
#define LOG2E 1.4426950408889634f

// Segment bounds: {0,100,200,296,396,492,592,688,784} — all %4==0
// ws: VW [392 pairs][4 hb][V0 256|W0 256|V1 256|W1 256] = 6.42 MB
//   | G [7][B][H] partial-range GEMMs (*log2e)          = 29.4 MB
//   | part [4][B][D]                                    = 12.8 MB

__device__ __forceinline__ int seg_lo(int s) {
    switch (s) {
        case 0: return 0;   case 1: return 100; case 2: return 200; case 3: return 296;
        case 4: return 396; case 5: return 492; case 6: return 592; default: return 688;
    }
}
__device__ __forceinline__ int seg_hi(int s) {
    switch (s) {
        case 0: return 100; case 1: return 200; case 2: return 296; case 3: return 396;
        case 4: return 492; case 5: return 592; case 6: return 688; default: return 784;
    }
}

// ---------- fat prep kernel ----------
// blocks [0,800):    build VW (V copy + W transpose*log2e) for a 32i x 32h tile
// blocks [800,2592): partial-range GEMM G[r][b][h] = sum_{j in range r} px[b][j]*W[h][j]*log2e
__global__ __launch_bounds__(256) void prep(const float* __restrict__ V,
                                            const float* __restrict__ W,
                                            const float* __restrict__ px,
                                            float* __restrict__ VW,
                                            float* __restrict__ G) {
    __shared__ float smem[32 * 33];
    const int t = threadIdx.x;

    if (blockIdx.x < 800) {
        // ---- build VW ----
        int i0 = (blockIdx.x % 25) * 32;    // D tile
        int h0 = (blockIdx.x / 25) * 32;    // H tile
        int tx = t & 31, ty = t >> 5;       // 32 x 8
        // addr of V element (i,h): (i>>1)*4096 + (h>>8)*1024 + (i&1)*512 + (h&255); W: +256
        // V copy
#pragma unroll
        for (int j = 0; j < 4; ++j) {
            int i = i0 + ty + j * 8;
            int h = h0 + tx;
            if (i < D_)
                VW[(size_t)(i >> 1) * 4096 + (h >> 8) * 1024 + (i & 1) * 512 + (h & 255)]
                    = V[(size_t)i * H_ + h];
        }
        // W transpose via LDS, *log2e
#pragma unroll
        for (int j = 0; j < 4; ++j) {
            int h = h0 + ty + j * 8;
            int i = i0 + tx;
            float v = 0.f;
            if (i < D_) v = W[(size_t)h * D_ + i] * LOG2E;
            smem[(ty + j * 8) * 33 + tx] = v;
        }
        __syncthreads();
#pragma unroll
        for (int j = 0; j < 4; ++j) {
            int i = i0 + ty + j * 8;
            int h = h0 + tx;
            if (i < D_)
                VW[(size_t)(i >> 1) * 4096 + (h >> 8) * 1024 + (i & 1) * 512 + 256 + (h & 255)]
                    = smem[tx * 33 + ty + j * 8];
        }
    } else {
        // ---- partial GEMM ----
        float* xs = smem;            // [4][64]
        float* ws = smem + 256;      // [4][64]
        int idx = blockIdx.x - 800;
        int r   = idx >> 8;          // range 0..6
        int b0  = (idx & 15) * 64;
        int h0  = ((idx >> 4) & 15) * 64;
        int j0s = seg_lo(r), j1s = seg_hi(r);

        const int tb = t >> 4, th = t & 15;   // 16x16, each 4b x 4h
        float acc[4][4];
#pragma unroll
        for (int bi = 0; bi < 4; ++bi)
#pragma unroll
            for (int hi = 0; hi < 4; ++hi) acc[bi][hi] = 0.f;

        for (int j0 = j0s; j0 < j1s; j0 += 4) {
            float xv = px[(size_t)(b0 + (t >> 2)) * D_ + j0 + (t & 3)];
            float4 wv = make_float4(0, 0, 0, 0);
            if (t < 64) wv = *(const float4*)(W + (size_t)(h0 + t) * D_ + j0);
            __syncthreads();
            xs[(t & 3) * 64 + (t >> 2)] = xv;
            if (t < 64) {
                ws[0 * 64 + t] = wv.x * LOG2E;
                ws[1 * 64 + t] = wv.y * LOG2E;
                ws[2 * 64 + t] = wv.z * LOG2E;
                ws[3 * 64 + t] = wv.w * LOG2E;
            }
            __syncthreads();
#pragma unroll
            for (int jj = 0; jj < 4; ++jj) {
                float4 xb = *(float4*)&xs[jj * 64 + tb * 4];
                float4 wb = *(float4*)&ws[jj * 64 + th * 4];
                float xa[4] = {xb.x, xb.y, xb.z, xb.w};
                float wa[4] = {wb.x, wb.y, wb.z, wb.w};
#pragma unroll
                for (int bi = 0; bi < 4; ++bi)
#pragma unroll
                    for (int hi = 0; hi < 4; ++hi)
                        acc[bi][hi] = fmaf(xa[bi], wa[hi], acc[bi][hi]);
            }
        }
        float* dst = G + (size_t)r * BH_;
#pragma unroll
        for (int bi = 0; bi < 4; ++bi) {
            float4 o = make_float4(acc[bi][0], acc[bi][1], acc[bi][2], acc[bi][3]);
            *(float4*)(dst + (size_t)(b0 + tb * 4 + bi) * H_ + h0 + th * 4) = o;
        }
    }
}

// ---------- DPP reduce: both 32-lane halves simultaneously ----------
template <int CTRL>
__device__ __forceinline__ float dpp_add(float p) {
    int s = __builtin_amdgcn_update_dpp(0, __float_as_int(p), CTRL, 0xf, 0xf, true);
    return p + __int_as_float(s);
}
__device__ __forceinline__ float reduce_halves(float p) {
    p = dpp_add<0x111>(p);
    p = dpp_add<0x112>(p);
    p = dpp_add<0x114>(p);
    p = dpp_add<0x118>(p);
    p = dpp_add<0x142>(p);   // lane31 = sum(0..31), lane63 = sum(32..63)
    return p;
}

// ---------- main NADE scan: 8 D-segments x 4 hb x 512 row-pairs = 16384 waves ----------
__global__ __launch_bounds__(256, 8) void nade_main(
    const float* __restrict__ px,   // [B, D]
    const float* __restrict__ c,    // [H]
    const float* __restrict__ VW,   // pair-interleaved
    const float* __restrict__ G,    // [7][B][H] partial GEMMs (log2 domain)
    float* __restrict__ part)       // [4][B][D]
{
    const int lane = threadIdx.x & 63;
    const int wid  = threadIdx.x >> 6;
    const int gw   = blockIdx.x * 4 + wid;   // 0..16383
    const int s    = gw & 7;
    const int hb   = (gw >> 3) & 3;
    const int rp   = gw >> 5;                // 0..511
    const int half = lane >> 5;
    const int row  = rp * 2 + half;
    const int hl   = lane & 31;
    const int h0   = hb * 256 + hl * 8;

    const int i0s = seg_lo(s), i1s = seg_hi(s);

    // init A = c*log2e + sum_{r<s} G_r   (log2 domain)
    float A[8];
    {
        float4 a0 = *(const float4*)(c + h0);
        float4 a1 = *(const float4*)(c + h0 + 4);
        A[0] = a0.x * LOG2E; A[1] = a0.y * LOG2E; A[2] = a0.z * LOG2E; A[3] = a0.w * LOG2E;
        A[4] = a1.x * LOG2E; A[5] = a1.y * LOG2E; A[6] = a1.z * LOG2E; A[7] = a1.w * LOG2E;
        for (int r = 0; r < s; ++r) {
            const float* gp = G + (size_t)r * BH_ + (size_t)row * H_ + h0;
            float4 g0 = *(const float4*)(gp);
            float4 g1 = *(const float4*)(gp + 4);
            A[0] += g0.x; A[1] += g0.y; A[2] += g0.z; A[3] += g0.w;
            A[4] += g1.x; A[5] += g1.y; A[6] += g1.z; A[7] += g1.w;
        }
    }

    const float* xp = px + (size_t)row * D_;
    float*       pp = part + ((size_t)hb * B_ + row) * D_;
    // lane base into VW for step i0s (i0s is even): pair = i0s>>1
    const float* vwA = VW + (size_t)(i0s >> 1) * 4096 + hb * 1024 + hl * 8;
    const float* vwB = vwA + 4096;   // next pair

    // one step (8 h): grouped rcp over 8 q's, clamp 15 so prod(q) < 2^120
    auto step8 = [&A](const float4& v0, const float4& v1,
                      const float4& w0, const float4& w1, float xi) -> float {
        float va[8] = {v0.x, v0.y, v0.z, v0.w, v1.x, v1.y, v1.z, v1.w};
        float wa[8] = {w0.x, w0.y, w0.z, w0.w, w1.x, w1.y, w1.z, w1.w};
        float q[8];
#pragma unroll
        for (int k = 0; k < 8; ++k) {
            float e = __builtin_amdgcn_exp2f(fminf(15.f, -A[k]));
            q[k] = 1.f + e;
            A[k] = fmaf(wa[k], xi, A[k]);
        }
        float a01 = fmaf(va[0], q[1], va[1] * q[0]);
        float a23 = fmaf(va[2], q[3], va[3] * q[2]);
        float a45 = fmaf(va[4], q[5], va[5] * q[4]);
        float a67 = fmaf(va[6], q[7], va[7] * q[6]);
        float q01 = q[0] * q[1], q23 = q[2] * q[3];
        float q45 = q[4] * q[5], q67 = q[6] * q[7];
        float n0123 = fmaf(a01, q23, a23 * q01);
        float n4567 = fmaf(a45, q67, a67 * q45);
        float q0123 = q01 * q23, q4567 = q45 * q67;
        float r = __builtin_amdgcn_rcpf(q0123 * q4567);
        float n = fmaf(n0123, q4567, n4567 * q0123);
        return n * r;
    };

    for (int ib = i0s; ib < i1s; ib += 4) {     // all segment lengths %4 == 0
        float4 xq = *(const float4*)(xp + ib);
        float xa[4] = {xq.x, xq.y, xq.z, xq.w};
        float pr[4];
        // steps 0,1 from vwA (offsets 0 / 1024B / 2048B / 3072B), steps 2,3 from vwB
        {
            float4 v0 = *(const float4*)(vwA + 0),   v1 = *(const float4*)(vwA + 4);
            float4 w0 = *(const float4*)(vwA + 256), w1 = *(const float4*)(vwA + 260);
            pr[0] = reduce_halves(step8(v0, v1, w0, w1, xa[0]));
        }
        {
            float4 v0 = *(const float4*)(vwA + 512), v1 = *(const float4*)(vwA + 516);
            float4 w0 = *(const float4*)(vwA + 768), w1 = *(const float4*)(vwA + 772);
            pr[1] = reduce_halves(step8(v0, v1, w0, w1, xa[1]));
        }
        {
            float4 v0 = *(const float4*)(vwB + 0),   v1 = *(const float4*)(vwB + 4);
            float4 w0 = *(const float4*)(vwB + 256), w1 = *(const float4*)(vwB + 260);
            pr[2] = reduce_halves(step8(v0, v1, w0, w1, xa[2]));
        }
        {
            float4 v0 = *(const float4*)(vwB + 512), v1 = *(const float4*)(vwB + 516);
            float4 w0 = *(const float4*)(vwB + 768), w1 = *(const float4*)(vwB + 772);
            pr[3] = reduce_halves(step8(v0, v1, w0, w1, xa[3]));
        }
        vwA += 8192; vwB += 8192;
        if (hl == 31) {
            float4 o = make_float4(pr[0], pr[1], pr[2], pr[3]);
            *(float4*)(pp + ib) = o;
        }
    }
}

// ---------- epilogue: out[row][i] = bias[i] + sum_hb part[hb][row][i] ----------
__global__ __launch_bounds__(256) void reduce_out(const float* __restrict__ part,
                                                  const float* __restrict__ bias,
                                                  float* __restrict__ out) {
    int t = blockIdx.x * 256 + threadIdx.x;
    if (t >= B_ * (D_ / 4)) return;
    int row = t / (D_ / 4);
    int ic  = (t - row * (D_ / 4)) * 4;
    float4 acc = *(const float4*)(bias + ic);
    const float* p = part + (size_t)row * D_ + ic;
#pragma unroll
    for (int hb = 0; hb < 4; ++hb) {
        float4 v = *(const float4*)(p + (size_t)hb * B_ * D_);
        acc.x += v.x; acc.y += v.y; acc.z += v.z; acc.w += v.w;
    }
    *(float4*)(out + (size_t)row * D_ + ic) = acc;
}

extern "C" void kernel_launch(void* const* d_in, const int* in_sizes, int n_in,
                              void* d_out, int out_size, void* d_ws, size_t ws_size,
                              hipStream_t stream) {
    const float* px   = (const float*)d_in[0];  // [B, D]
    const float* W    = (const float*)d_in[1];  // [H, D]
    const float* c    = (const float*)d_in[2];  // [H]
    const float* V    = (const float*)d_in[3];  // [D, H]
    const float* bias = (const float*)d_in[4];  // [D]
    float* out = (float*)d_out;                 // [B, D]

    float* VW   = (float*)d_ws;                 // 392*4096 floats = 6.42 MB
    float* G    = VW + (size_t)392 * 4096;      // [7][B][H] = 29.4 MB
    float* part = G + (size_t)7 * BH_;          // [4][B][D] = 12.8 MB

    prep<<<dim3(2592), 256, 0, stream>>>(V, W, px, VW, G);

    // 4096 blocks x 4 waves = 16384 waves = 2 full residency rounds
    nade_main<<<dim3(4096), 256, 0, stream>>>(px, c, VW, G, part);

    reduce_out<<<dim3((B_ * (D_ / 4) + 255) / 256), 256, 0, stream>>>(part, bias, out);
}